// Round 18
// baseline (235.711 us; speedup 1.0000x reference)
//
#include <hip/hip_runtime.h>
#include <math.h>

using f32x4  = __attribute__((ext_vector_type(4))) float;
using bf16x8 = __attribute__((ext_vector_type(8))) short;

typedef const __attribute__((address_space(1))) void gas_void;
typedef __attribute__((address_space(3))) void las_void;

__device__ __forceinline__ void gl16(const void* g, void* l) {
    __builtin_amdgcn_global_load_lds((gas_void*)g, (las_void*)l, 16, 0, 0);
}

__device__ __forceinline__ unsigned short f2bf(float f) {
    union { float f; unsigned u; } v; v.f = f;
    unsigned r = v.u + 0x7fffu + ((v.u >> 16) & 1u);   // RNE
    return (unsigned short)(r >> 16);
}
__device__ __forceinline__ float bf2f(unsigned short u) {
    return __uint_as_float(((unsigned)u) << 16);
}

#define VW12() asm volatile("s_waitcnt vmcnt(12)" ::: "memory")
#define VW0() asm volatile("s_waitcnt vmcnt(0)" ::: "memory")
#define BAR() __builtin_amdgcn_s_barrier()

// ---------------- prep: X (NCHW fp32) -> patch-major bf16 Xp[36864][768] ----------------
__global__ void pcl_prep_x(const float* __restrict__ x, unsigned short* __restrict__ xp) {
    int t = threadIdx.x;              // 256
    int wv = t >> 6, l = t & 63;
    int p = blockIdx.x * 4 + wv;      // patch id
    int b = p / 576, n = p % 576;
    int ph = n / 24, pw = n % 24;
    const float* base = x + ((size_t)(b * 3)) * 147456 + (ph * 16) * 384 + pw * 16;
    unsigned* dst = (unsigned*)(xp + (size_t)p * 768);
#pragma unroll
    for (int q = 0; q < 6; ++q) {
        int k = q * 128 + l * 2;
        int c = k >> 8, i = (k >> 4) & 15, j = k & 15;
        const float* s = base + (size_t)c * 147456 + i * 384 + j;
        float2 v = *(const float2*)s;
        unsigned lo = f2bf(v.x), hi = f2bf(v.y);
        dst[q * 64 + l] = lo | (hi << 16);
    }
}

// ---- prep: W -> bf16 row-major (k1 B); latents -> row-normalized bf16 FRAGMENT layout ----
// lfrag fragment block (1024B): (ns, kt, nb, ks); lane l = (col&15) + 16*((k%32)/8).
__global__ void pcl_prep_wl(const float* __restrict__ w,
                            const float* __restrict__ l1, const float* __restrict__ l2,
                            unsigned short* __restrict__ wsW,
                            unsigned short* __restrict__ lfrag) {
    int r = blockIdx.x, t = threadIdx.x;   // 2816 x 64
    if (r < 768) {
        const float* src = w + (size_t)r * 768;
        unsigned short* dst = wsW + (size_t)r * 768;
#pragma unroll
        for (int i = 0; i < 12; ++i) dst[t + 64 * i] = f2bf(src[t + 64 * i]);
    } else {
        int lr = r - 768;
        const float* src = (lr < 1024) ? l1 + (size_t)lr * 768 : l2 + (size_t)(lr - 1024) * 768;
        float vals[12];
        float s = 0.f;
#pragma unroll
        for (int i = 0; i < 12; ++i) {
            float f = bf2f(f2bf(src[t + 64 * i]));
            vals[i] = f; s += f * f;
        }
#pragma unroll
        for (int off = 32; off; off >>= 1) s += __shfl_xor(s, off, 64);
        float rn = 1.0f / sqrtf(s);
        int ns = lr >> 6, nb = (lr >> 4) & 3, c16 = lr & 15;
        int ks = t >> 5, lh = (t >> 3) & 3, jj = t & 7;
        int lane = c16 + 16 * lh;
#pragma unroll
        for (int i = 0; i < 12; ++i) {
            int fb = ns * 96 + i * 8 + nb * 2 + ks;    // k = i*64 + t -> kt = i
            lfrag[(size_t)fb * 512 + lane * 8 + jj] = f2bf(vals[i] * rn);
        }
    }
}

// ================= K1': conv GEMM 192x96 tiles, 2 blocks/CU (R12-proven) =============
// Epilogue writes P in k2-fragment layout: block (S, kt, m, ks), lane = (row&15)+16*((d%32)/8).
#define K1_LDS 81920

__global__ __launch_bounds__(256, 2)
void pcl_k1(const unsigned short* __restrict__ xp,
            const unsigned short* __restrict__ wsW,
            const float* __restrict__ bias,
            unsigned short* __restrict__ pfrag,
            float* __restrict__ rpnp) {
    extern __shared__ char smem[];
    const int t = threadIdx.x, w = t >> 6, l = t & 63;
    const int wg = (blockIdx.x & 7) * 192 + (blockIdx.x >> 3);   // bijective XCD remap
    const int mt = wg >> 3, nt = wg & 7;
    const size_t Mb = (size_t)mt * 192;
    const int Nb = nt * 96;
    const int wm = w >> 1, wn = w & 1;
    const int ir = l >> 3, s2 = (l & 7) ^ ir;
    const int lm = l & 15, lg4 = l >> 4;

    char* buf0 = smem;
    char* buf1 = smem + 40960;

    auto stage = [&](int kt, char* buf) {            // A 6 + B 3 chunks per wave
#pragma unroll
        for (int rr = 0; rr < 6; ++rr) {
            int c2 = w * 6 + rr;                     // 0..23
            gl16(xp + (Mb + c2 * 8 + ir) * 768 + kt * 64 + s2 * 8, buf + c2 * 1024);
        }
#pragma unroll
        for (int rr = 0; rr < 3; ++rr) {
            int c2 = w * 3 + rr;                     // 0..11
            gl16(wsW + (size_t)(Nb + c2 * 8 + ir) * 768 + kt * 64 + s2 * 8,
                 buf + 24576 + c2 * 1024);
        }
    };

    f32x4 acc[6][3];
#pragma unroll
    for (int m = 0; m < 6; ++m)
#pragma unroll
        for (int nb = 0; nb < 3; ++nb) acc[m][nb] = (f32x4)0.f;

    stage(0, buf0);
    VW0(); BAR();

    bf16x8 areg[3][2], breg[3][2];

#pragma unroll 2
    for (int kt = 0; kt < 12; ++kt) {
        char* cur = (kt & 1) ? buf1 : buf0;
        char* nxt = (kt & 1) ? buf0 : buf1;

        if (kt < 11) stage(kt + 1, nxt);

#pragma unroll
        for (int nb = 0; nb < 3; ++nb)
#pragma unroll
            for (int ks = 0; ks < 2; ++ks) {
                int rb = wn * 48 + nb * 16 + lm, slot = ks * 4 + lg4;
                breg[nb][ks] = *(const bf16x8*)(cur + 24576 + rb * 128 + ((slot ^ (rb & 7)) << 4));
            }
#pragma unroll
        for (int m = 0; m < 3; ++m)
#pragma unroll
            for (int ks = 0; ks < 2; ++ks) {
                int r = wm * 96 + m * 16 + lm, slot = ks * 4 + lg4;
                areg[m][ks] = *(const bf16x8*)(cur + r * 128 + ((slot ^ (r & 7)) << 4));
            }
        __builtin_amdgcn_s_setprio(1);
#pragma unroll
        for (int m = 0; m < 3; ++m)
#pragma unroll
            for (int nb = 0; nb < 3; ++nb)
#pragma unroll
                for (int ks = 0; ks < 2; ++ks)
                    acc[m][nb] = __builtin_amdgcn_mfma_f32_16x16x32_bf16(areg[m][ks], breg[nb][ks], acc[m][nb], 0, 0, 0);
        __builtin_amdgcn_s_setprio(0);

#pragma unroll
        for (int m = 0; m < 3; ++m)
#pragma unroll
            for (int ks = 0; ks < 2; ++ks) {
                int r = wm * 96 + 48 + m * 16 + lm, slot = ks * 4 + lg4;
                areg[m][ks] = *(const bf16x8*)(cur + r * 128 + ((slot ^ (r & 7)) << 4));
            }
        __builtin_amdgcn_s_setprio(1);
#pragma unroll
        for (int m = 0; m < 3; ++m)
#pragma unroll
            for (int nb = 0; nb < 3; ++nb)
#pragma unroll
                for (int ks = 0; ks < 2; ++ks)
                    acc[3 + m][nb] = __builtin_amdgcn_mfma_f32_16x16x32_bf16(areg[m][ks], breg[nb][ks], acc[3 + m][nb], 0, 0, 0);
        __builtin_amdgcn_s_setprio(0);

        VW0();
        BAR();
    }

    // ---- epilogue: bias, bf16 P store in FRAGMENT layout, partial row sumsq ----
    float rs[6][4];
#pragma unroll
    for (int m = 0; m < 6; ++m)
#pragma unroll
        for (int j = 0; j < 4; ++j) rs[m][j] = 0.f;
    const int S = mt * 2 + wm;
#pragma unroll
    for (int nb = 0; nb < 3; ++nb) {
        int d = Nb + wn * 48 + nb * 16 + lm;
        float bv = bias[d];
        int kt = d >> 6, ks = (d >> 5) & 1, lh = (d >> 3) & 3, jj = d & 7;
#pragma unroll
        for (int m = 0; m < 6; ++m) {
            int mh = m / 3, mi = m % 3;
            int fb = S * 144 + kt * 12 + (mh * 3 + mi) * 2 + ks;
#pragma unroll
            for (int j = 0; j < 4; ++j) {
                int lane = (lg4 * 4 + j) + 16 * lh;
                unsigned short h = f2bf(acc[m][nb][j] + bv);
                pfrag[(size_t)fb * 512 + lane * 8 + jj] = h;
                float fv = bf2f(h);
                rs[m][j] += fv * fv;
            }
        }
    }
#pragma unroll
    for (int m = 0; m < 6; ++m)
#pragma unroll
        for (int j = 0; j < 4; ++j) {
            rs[m][j] += __shfl_xor(rs[m][j], 1);
            rs[m][j] += __shfl_xor(rs[m][j], 2);
            rs[m][j] += __shfl_xor(rs[m][j], 4);
            rs[m][j] += __shfl_xor(rs[m][j], 8);
        }
    __syncthreads();
    float* nrm = (float*)smem;     // [192][2]
    if (lm == 0) {
#pragma unroll
        for (int m = 0; m < 6; ++m) {
            int mh = m / 3, mi = m % 3;
#pragma unroll
            for (int j = 0; j < 4; ++j) {
                int row = wm * 96 + mh * 48 + mi * 16 + lg4 * 4 + j;
                nrm[row * 2 + wn] = rs[m][j];
            }
        }
    }
    __syncthreads();
    if (t < 192) rpnp[(size_t)nt * 36864 + Mb + t] = nrm[t * 2] + nrm[t * 2 + 1];
}

// ---------------- norm: rpn = rsqrt(sum of 8 partials) ----------------
__global__ void pcl_norm(const float* __restrict__ rpnp, float* __restrict__ rpn) {
    int i = blockIdx.x * 256 + threadIdx.x;   // 144 x 256 = 36864
    float s = 0.f;
#pragma unroll
    for (int nt = 0; nt < 8; ++nt) s += rpnp[(size_t)nt * 36864 + i];
    rpn[i] = 1.0f / sqrtf(s);
}

// ================= K2: fat-wave score GEMM 192x256, A-regs-dbuf + B-LDS ==============
// grid 1536 = 192 mt x 8 nt; XCD remap; 256 thr = 4 waves 2(M)x2(N), wave tile 96x128.
// A: coalesced 1024B frag loads from pfrag, double-buffered in regs (TA pipe only).
// B: gl16 -> LDS linear frag blocks (32 x 1024B per kt, dbuf 2x32K), lane-contiguous
// conflict-free ds_read_b128 x16/wave/kt. Per CU-kt: TA ~1250cyc, LDS ~960, MFMA 466.
// launch_bounds(256,1): 1 wave/SIMD, 512 unified regs (acc 192 AGPR + A 96 + B 64).
// MFMA ks-outer => dependent accumulates 48 apart. vmcnt(12) drains exactly B's 8 gl16.
#define K2_LDS 65536

__global__ __launch_bounds__(256, 1)
void pcl_k2(const unsigned short* __restrict__ pfrag,
            const unsigned short* __restrict__ lfrag,
            const float* __restrict__ rpn,
            double* __restrict__ partials) {
    extern __shared__ char smem[];
    const int t = threadIdx.x, w = t >> 6, l = t & 63;
    const int wg = (blockIdx.x & 7) * 192 + (blockIdx.x >> 3);   // bijective XCD remap
    const int mt = wg >> 3, nt = wg & 7;
    const int wm = w >> 1, wn = w & 1;
    const int lg4 = l >> 4;
    const int S = mt * 2 + wm;           // 96-row A strip (0..383)
    const int nsBase = nt * 4;           // four 64-col B strips per block

    char* buf0 = smem;
    char* buf1 = smem + 32768;

    auto stageB = [&](int kt, char* buf) {           // 32 blocks, 8 per wave
#pragma unroll
        for (int rr = 0; rr < 8; ++rr) {
            int c2 = w * 8 + rr;                     // 0..31: strip=c2>>3, (nb,ks)=c2&7
            int blkid = (nsBase + (c2 >> 3)) * 96 + kt * 8 + (c2 & 7);
            gl16((const char*)lfrag + ((size_t)blkid << 10) + l * 16, buf + c2 * 1024);
        }
    };

    const char* Ab = (const char*)pfrag + (((size_t)S * 144) << 10) + l * 16;

    f32x4 acc[6][8];
#pragma unroll
    for (int m = 0; m < 6; ++m)
#pragma unroll
        for (int nb = 0; nb < 8; ++nb) acc[m][nb] = (f32x4)0.f;

    bf16x8 aC[6][2], aN[6][2], breg[8][2];

    auto loadA = [&](int kt, bf16x8 (&dst)[6][2]) {
#pragma unroll
        for (int m = 0; m < 6; ++m)
#pragma unroll
            for (int ks = 0; ks < 2; ++ks)
                dst[m][ks] = *(const bf16x8*)(Ab + ((size_t)(kt * 12 + m * 2 + ks) << 10));
    };

    // prologue
    stageB(0, buf0);
    loadA(0, aC);
    VW0(); BAR();

    auto body = [&](int kt, bf16x8 (&aU)[6][2], bf16x8 (&aN2)[6][2], char* cur, char* nxt) {
        if (kt < 11) { stageB(kt + 1, nxt); loadA(kt + 1, aN2); }
        // B frags from LDS (lane-contiguous, conflict-free)
#pragma unroll
        for (int nb = 0; nb < 8; ++nb)
#pragma unroll
            for (int ks = 0; ks < 2; ++ks) {
                int c2 = (wn * 2 + (nb >> 2)) * 8 + (nb & 3) * 2 + ks;
                breg[nb][ks] = *(const bf16x8*)(cur + c2 * 1024 + l * 16);
            }
        __builtin_amdgcn_s_setprio(1);
#pragma unroll
        for (int ks = 0; ks < 2; ++ks)      // ks outer: dependent accumulates 48 apart
#pragma unroll
            for (int m = 0; m < 6; ++m)
#pragma unroll
                for (int nb = 0; nb < 8; ++nb)
                    acc[m][nb] = __builtin_amdgcn_mfma_f32_16x16x32_bf16(aU[m][ks], breg[nb][ks], acc[m][nb], 0, 0, 0);
        __builtin_amdgcn_s_setprio(0);
        if (kt < 11) { VW12(); } else { VW0(); }
        BAR();
    };

    for (int kp = 0; kp < 6; ++kp) {
        body(2 * kp,     aC, aN, buf0, buf1);
        body(2 * kp + 1, aN, aC, buf1, buf0);
    }

    // epilogue: exp(2*cos*rpn); strip S lies in one batch (96 | 576)
    double ssum = 0.0;
#pragma unroll
    for (int m = 0; m < 6; ++m) {
        int rl = S * 96 + m * 16;
        float rv[4];
#pragma unroll
        for (int j = 0; j < 4; ++j) rv[j] = rpn[rl + lg4 * 4 + j];
        float es = 0.f;
#pragma unroll
        for (int nb = 0; nb < 8; ++nb)
#pragma unroll
            for (int j = 0; j < 4; ++j)
                es += __expf(2.0f * acc[m][nb][j] * rv[j]);
        ssum += (double)es;
    }
#pragma unroll
    for (int off = 32; off; off >>= 1) ssum += __shfl_down(ssum, off);
    __syncthreads();
    double* red = (double*)smem;
    if (l == 0) red[w] = ssum;
    __syncthreads();
    if (t == 0) {
        double s = 0.0;
#pragma unroll
        for (int i = 0; i < 4; ++i) s += red[i];
        partials[wg] = s;
    }
}

// ---------------- finish: per-batch gather (3 mt x 8 nt), log-ratio, mean --------
__global__ void pcl_finish(const double* __restrict__ partials, float* __restrict__ out) {
    int b = threadIdx.x;   // 64 batches
    double far = 0.0, close = 0.0;
#pragma unroll
    for (int i = 0; i < 3; ++i) {
        int mt = b * 3 + i;
#pragma unroll
        for (int nTile = 0; nTile < 8; ++nTile) {
            double v = partials[mt * 8 + nTile];
            if (nTile < 4) far += v; else close += v;
        }
    }
    double lb = log(far) - log(close);
#pragma unroll
    for (int off = 32; off; off >>= 1) lb += __shfl_down(lb, off);
    if (b == 0) out[0] = (float)(lb * (1.0 / 64.0));
}

extern "C" void kernel_launch(void* const* d_in, const int* in_sizes, int n_in,
                              void* d_out, int out_size, void* d_ws, size_t ws_size,
                              hipStream_t stream) {
    const float* x    = (const float*)d_in[0];
    const float* w    = (const float*)d_in[1];
    const float* bias = (const float*)d_in[2];
    const float* l1   = (const float*)d_in[3];
    const float* l2   = (const float*)d_in[4];
    float* out = (float*)d_out;

    unsigned short* xp    = (unsigned short*)d_ws;                        // 36864*768 bf16 X
    unsigned short* pfrag = (unsigned short*)((char*)d_ws + 56623104);    // 36864*768 bf16 P frags
    unsigned short* wsW   = (unsigned short*)((char*)d_ws + 113246208);   // 768*768 bf16
    unsigned short* lfrag = (unsigned short*)((char*)d_ws + 114425856);   // 2048*768 bf16 L frags
    float* rpnp           = (float*)((char*)d_ws + 117571584);            // 8*36864 f32
    float* rpn            = (float*)((char*)d_ws + 118751232);            // 36864 f32
    double* partials      = (double*)((char*)d_ws + 118898688);           // 1536 f64

    (void)hipFuncSetAttribute((const void*)pcl_k1,
                              hipFuncAttributeMaxDynamicSharedMemorySize, K1_LDS);
    (void)hipFuncSetAttribute((const void*)pcl_k2,
                              hipFuncAttributeMaxDynamicSharedMemorySize, K2_LDS);

    pcl_prep_x<<<9216, 256, 0, stream>>>(x, xp);
    pcl_prep_wl<<<2816, 64, 0, stream>>>(w, l1, l2, wsW, lfrag);
    pcl_k1<<<1536, 256, K1_LDS, stream>>>(xp, wsW, bias, pfrag, rpnp);
    pcl_norm<<<144, 256, 0, stream>>>(rpnp, rpn);
    pcl_k2<<<1536, 256, K2_LDS, stream>>>(pfrag, lfrag, rpn, partials);
    pcl_finish<<<1, 64, 0, stream>>>(partials, out);
}

// Round 19
// 196.472 us; speedup vs baseline: 1.1997x; 1.1997x over previous
//
#include <hip/hip_runtime.h>
#include <math.h>

using f32x4  = __attribute__((ext_vector_type(4))) float;
using bf16x8 = __attribute__((ext_vector_type(8))) short;

typedef const __attribute__((address_space(1))) void gas_void;
typedef __attribute__((address_space(3))) void las_void;

__device__ __forceinline__ void gl16(const void* g, void* l) {
    __builtin_amdgcn_global_load_lds((gas_void*)g, (las_void*)l, 16, 0, 0);
}

__device__ __forceinline__ unsigned short f2bf(float f) {
    union { float f; unsigned u; } v; v.f = f;
    unsigned r = v.u + 0x7fffu + ((v.u >> 16) & 1u);   // RNE
    return (unsigned short)(r >> 16);
}
__device__ __forceinline__ float bf2f(unsigned short u) {
    return __uint_as_float(((unsigned)u) << 16);
}

#define VW0() asm volatile("s_waitcnt vmcnt(0)" ::: "memory")
#define BAR() __builtin_amdgcn_s_barrier()

// ---------------- prep: X (NCHW fp32) -> patch-major bf16 Xp[36864][768] ----------------
__global__ void pcl_prep_x(const float* __restrict__ x, unsigned short* __restrict__ xp) {
    int t = threadIdx.x;              // 256
    int wv = t >> 6, l = t & 63;
    int p = blockIdx.x * 4 + wv;      // patch id
    int b = p / 576, n = p % 576;
    int ph = n / 24, pw = n % 24;
    const float* base = x + ((size_t)(b * 3)) * 147456 + (ph * 16) * 384 + pw * 16;
    unsigned* dst = (unsigned*)(xp + (size_t)p * 768);
#pragma unroll
    for (int q = 0; q < 6; ++q) {
        int k = q * 128 + l * 2;
        int c = k >> 8, i = (k >> 4) & 15, j = k & 15;
        const float* s = base + (size_t)c * 147456 + i * 384 + j;
        float2 v = *(const float2*)s;
        unsigned lo = f2bf(v.x), hi = f2bf(v.y);
        dst[q * 64 + l] = lo | (hi << 16);
    }
}

// ---------------- prep: W -> bf16; latents -> row-normalized bf16 ----------------
__global__ void pcl_prep_wl(const float* __restrict__ w,
                            const float* __restrict__ l1, const float* __restrict__ l2,
                            unsigned short* __restrict__ wsW,
                            unsigned short* __restrict__ wsL) {
    int r = blockIdx.x, t = threadIdx.x;   // 2816 x 64
    if (r < 768) {
        const float* src = w + (size_t)r * 768;
        unsigned short* dst = wsW + (size_t)r * 768;
#pragma unroll
        for (int i = 0; i < 12; ++i) dst[t + 64 * i] = f2bf(src[t + 64 * i]);
    } else {
        int lr = r - 768;
        const float* src = (lr < 1024) ? l1 + (size_t)lr * 768 : l2 + (size_t)(lr - 1024) * 768;
        unsigned short* dst = wsL + (size_t)lr * 768;
        float vals[12];
        float s = 0.f;
#pragma unroll
        for (int i = 0; i < 12; ++i) {
            float f = bf2f(f2bf(src[t + 64 * i]));
            vals[i] = f; s += f * f;
        }
#pragma unroll
        for (int off = 32; off; off >>= 1) s += __shfl_xor(s, off, 64);
        float rn = 1.0f / sqrtf(s);
#pragma unroll
        for (int i = 0; i < 12; ++i) dst[t + 64 * i] = f2bf(vals[i] * rn);
    }
}

// ================= K1': conv GEMM 192x96 tiles, k2-clone, 2 blocks/CU (R12) ==========
#define K1_LDS 81920

__global__ __launch_bounds__(256, 2)
void pcl_k1(const unsigned short* __restrict__ xp,
            const unsigned short* __restrict__ wsW,
            const float* __restrict__ bias,
            unsigned short* __restrict__ pbuf,
            float* __restrict__ rpnp) {
    extern __shared__ char smem[];
    const int t = threadIdx.x, w = t >> 6, l = t & 63;
    const int wg = (blockIdx.x & 7) * 192 + (blockIdx.x >> 3);   // bijective XCD remap
    const int mt = wg >> 3, nt = wg & 7;
    const size_t Mb = (size_t)mt * 192;
    const int Nb = nt * 96;
    const int wm = w >> 1, wn = w & 1;
    const int ir = l >> 3, s2 = (l & 7) ^ ir;
    const int lm = l & 15, lg4 = l >> 4;

    char* buf0 = smem;
    char* buf1 = smem + 40960;

    auto stage = [&](int kt, char* buf) {            // A 6 + B 3 chunks per wave
#pragma unroll
        for (int rr = 0; rr < 6; ++rr) {
            int c2 = w * 6 + rr;                     // 0..23
            gl16(xp + (Mb + c2 * 8 + ir) * 768 + kt * 64 + s2 * 8, buf + c2 * 1024);
        }
#pragma unroll
        for (int rr = 0; rr < 3; ++rr) {
            int c2 = w * 3 + rr;                     // 0..11
            gl16(wsW + (size_t)(Nb + c2 * 8 + ir) * 768 + kt * 64 + s2 * 8,
                 buf + 24576 + c2 * 1024);
        }
    };

    f32x4 acc[6][3];
#pragma unroll
    for (int m = 0; m < 6; ++m)
#pragma unroll
        for (int nb = 0; nb < 3; ++nb) acc[m][nb] = (f32x4)0.f;

    stage(0, buf0);
    VW0(); BAR();

    bf16x8 areg[3][2], breg[3][2];

#pragma unroll 2
    for (int kt = 0; kt < 12; ++kt) {
        char* cur = (kt & 1) ? buf1 : buf0;
        char* nxt = (kt & 1) ? buf0 : buf1;

        if (kt < 11) stage(kt + 1, nxt);

#pragma unroll
        for (int nb = 0; nb < 3; ++nb)
#pragma unroll
            for (int ks = 0; ks < 2; ++ks) {
                int rb = wn * 48 + nb * 16 + lm, slot = ks * 4 + lg4;
                breg[nb][ks] = *(const bf16x8*)(cur + 24576 + rb * 128 + ((slot ^ (rb & 7)) << 4));
            }
#pragma unroll
        for (int m = 0; m < 3; ++m)
#pragma unroll
            for (int ks = 0; ks < 2; ++ks) {
                int r = wm * 96 + m * 16 + lm, slot = ks * 4 + lg4;
                areg[m][ks] = *(const bf16x8*)(cur + r * 128 + ((slot ^ (r & 7)) << 4));
            }
        __builtin_amdgcn_s_setprio(1);
#pragma unroll
        for (int m = 0; m < 3; ++m)
#pragma unroll
            for (int nb = 0; nb < 3; ++nb)
#pragma unroll
                for (int ks = 0; ks < 2; ++ks)
                    acc[m][nb] = __builtin_amdgcn_mfma_f32_16x16x32_bf16(areg[m][ks], breg[nb][ks], acc[m][nb], 0, 0, 0);
        __builtin_amdgcn_s_setprio(0);

#pragma unroll
        for (int m = 0; m < 3; ++m)
#pragma unroll
            for (int ks = 0; ks < 2; ++ks) {
                int r = wm * 96 + 48 + m * 16 + lm, slot = ks * 4 + lg4;
                areg[m][ks] = *(const bf16x8*)(cur + r * 128 + ((slot ^ (r & 7)) << 4));
            }
        __builtin_amdgcn_s_setprio(1);
#pragma unroll
        for (int m = 0; m < 3; ++m)
#pragma unroll
            for (int nb = 0; nb < 3; ++nb)
#pragma unroll
                for (int ks = 0; ks < 2; ++ks)
                    acc[3 + m][nb] = __builtin_amdgcn_mfma_f32_16x16x32_bf16(areg[m][ks], breg[nb][ks], acc[3 + m][nb], 0, 0, 0);
        __builtin_amdgcn_s_setprio(0);

        VW0();
        BAR();
    }

    // ---- epilogue: bias, bf16 P store, partial row sumsq over this block's 96 cols ----
    float rs[6][4];
#pragma unroll
    for (int m = 0; m < 6; ++m)
#pragma unroll
        for (int j = 0; j < 4; ++j) rs[m][j] = 0.f;
#pragma unroll
    for (int nb = 0; nb < 3; ++nb) {
        int d = Nb + wn * 48 + nb * 16 + lm;
        float bv = bias[d];
#pragma unroll
        for (int m = 0; m < 6; ++m) {
            int mh = m / 3, mi = m % 3;
#pragma unroll
            for (int j = 0; j < 4; ++j) {
                int row = wm * 96 + mh * 48 + mi * 16 + lg4 * 4 + j;
                unsigned short h = f2bf(acc[m][nb][j] + bv);
                pbuf[(Mb + row) * 768 + d] = h;
                float fv = bf2f(h);
                rs[m][j] += fv * fv;
            }
        }
    }
#pragma unroll
    for (int m = 0; m < 6; ++m)
#pragma unroll
        for (int j = 0; j < 4; ++j) {
            rs[m][j] += __shfl_xor(rs[m][j], 1);
            rs[m][j] += __shfl_xor(rs[m][j], 2);
            rs[m][j] += __shfl_xor(rs[m][j], 4);
            rs[m][j] += __shfl_xor(rs[m][j], 8);
        }
    __syncthreads();
    float* nrm = (float*)smem;     // [192][2]
    if (lm == 0) {
#pragma unroll
        for (int m = 0; m < 6; ++m) {
            int mh = m / 3, mi = m % 3;
#pragma unroll
            for (int j = 0; j < 4; ++j) {
                int row = wm * 96 + mh * 48 + mi * 16 + lg4 * 4 + j;
                nrm[row * 2 + wn] = rs[m][j];
            }
        }
    }
    __syncthreads();
    if (t < 192) rpnp[(size_t)nt * 36864 + Mb + t] = nrm[t * 2] + nrm[t * 2 + 1];
}

// ---------------- norm: rpn = rsqrt(sum of 8 partials) ----------------
__global__ void pcl_norm(const float* __restrict__ rpnp, float* __restrict__ rpn) {
    int i = blockIdx.x * 256 + threadIdx.x;   // 144 x 256 = 36864
    float s = 0.f;
#pragma unroll
    for (int nt = 0; nt < 8; ++nt) s += rpnp[(size_t)nt * 36864 + i];
    rpn[i] = 1.0f / sqrtf(s);
}

// ================= K2: score GEMM 192x128, 2-phase (R12-proven) + anti-phase stagger ==
// grid 3072 = 192 mt x 16 nt; XCD remap; 256 thr, 4 waves 2Mx2N, wave 96x64;
// LDS 2x40K -> 2 blocks/CU. New: odd-slot co-resident blocks ((bid>>8)&1) sleep ~1.8k
// cycles DURING their prologue loads -> half-kt phase offset so the two blocks
// interleave LDS-phase and MFMA-phase instead of contending in lock-step.
#define K2_LDS 81920

__global__ __launch_bounds__(256, 2)
void pcl_k2(const unsigned short* __restrict__ pbuf,
            const unsigned short* __restrict__ wsL,
            const float* __restrict__ rpn,
            double* __restrict__ partials) {
    extern __shared__ char smem[];
    const int t = threadIdx.x, w = t >> 6, l = t & 63;
    const int wg = (blockIdx.x & 7) * 384 + (blockIdx.x >> 3);   // bijective XCD remap
    const int mt = wg >> 4, nt = wg & 15;
    const size_t Mb = (size_t)mt * 192;
    const int Nb = nt * 128;
    const int wm = w >> 1, wn = w & 1;
    const int ir = l >> 3, s2 = (l & 7) ^ ir;
    const int lm = l & 15, lg4 = l >> 4;

    char* buf0 = smem;
    char* buf1 = smem + 40960;

    auto stage = [&](int kt, char* buf) {            // A 6 + B 4 chunks per wave
#pragma unroll
        for (int rr = 0; rr < 6; ++rr) {
            int c2 = w * 6 + rr;                     // 0..23
            gl16(pbuf + (Mb + c2 * 8 + ir) * 768 + kt * 64 + s2 * 8, buf + c2 * 1024);
        }
#pragma unroll
        for (int rr = 0; rr < 4; ++rr) {
            int c2 = w * 4 + rr;                     // 0..15
            gl16(wsL + (size_t)(Nb + c2 * 8 + ir) * 768 + kt * 64 + s2 * 8,
                 buf + 24576 + c2 * 1024);
        }
    };

    f32x4 acc[6][4];
#pragma unroll
    for (int m = 0; m < 6; ++m)
#pragma unroll
        for (int nb = 0; nb < 4; ++nb) acc[m][nb] = (f32x4)0.f;

    stage(0, buf0);
    // anti-phase stagger: odd CU-slot blocks sleep ~1.8k cyc while tile-0 loads fly
    if ((blockIdx.x >> 8) & 1) {
        asm volatile("s_sleep 14");
        asm volatile("s_sleep 14");
    }
    VW0(); BAR();

    bf16x8 areg[3][2], breg[4][2];

#pragma unroll 2
    for (int kt = 0; kt < 12; ++kt) {
        char* cur = (kt & 1) ? buf1 : buf0;
        char* nxt = (kt & 1) ? buf0 : buf1;

        if (kt < 11) stage(kt + 1, nxt);

#pragma unroll
        for (int nb = 0; nb < 4; ++nb)
#pragma unroll
            for (int ks = 0; ks < 2; ++ks) {
                int rb = wn * 64 + nb * 16 + lm, slot = ks * 4 + lg4;
                breg[nb][ks] = *(const bf16x8*)(cur + 24576 + rb * 128 + ((slot ^ (rb & 7)) << 4));
            }
#pragma unroll
        for (int m = 0; m < 3; ++m)
#pragma unroll
            for (int ks = 0; ks < 2; ++ks) {
                int r = wm * 96 + m * 16 + lm, slot = ks * 4 + lg4;
                areg[m][ks] = *(const bf16x8*)(cur + r * 128 + ((slot ^ (r & 7)) << 4));
            }
        __builtin_amdgcn_s_setprio(1);
#pragma unroll
        for (int m = 0; m < 3; ++m)
#pragma unroll
            for (int nb = 0; nb < 4; ++nb)
#pragma unroll
                for (int ks = 0; ks < 2; ++ks)
                    acc[m][nb] = __builtin_amdgcn_mfma_f32_16x16x32_bf16(areg[m][ks], breg[nb][ks], acc[m][nb], 0, 0, 0);
        __builtin_amdgcn_s_setprio(0);

#pragma unroll
        for (int m = 0; m < 3; ++m)
#pragma unroll
            for (int ks = 0; ks < 2; ++ks) {
                int r = wm * 96 + 48 + m * 16 + lm, slot = ks * 4 + lg4;
                areg[m][ks] = *(const bf16x8*)(cur + r * 128 + ((slot ^ (r & 7)) << 4));
            }
        __builtin_amdgcn_s_setprio(1);
#pragma unroll
        for (int m = 0; m < 3; ++m)
#pragma unroll
            for (int nb = 0; nb < 4; ++nb)
#pragma unroll
                for (int ks = 0; ks < 2; ++ks)
                    acc[3 + m][nb] = __builtin_amdgcn_mfma_f32_16x16x32_bf16(areg[m][ks], breg[nb][ks], acc[3 + m][nb], 0, 0, 0);
        __builtin_amdgcn_s_setprio(0);

        VW0();
        BAR();
    }

    // epilogue: exp(2*cos*rpn); whole tile lies in one batch (192 | 576)
    double ssum = 0.0;
#pragma unroll
    for (int m = 0; m < 6; ++m) {
        int mh = m / 3, mi = m % 3;
        int rl = wm * 96 + mh * 48 + mi * 16;
        float rv[4];
#pragma unroll
        for (int j = 0; j < 4; ++j) rv[j] = rpn[Mb + rl + lg4 * 4 + j];
        float es = 0.f;
#pragma unroll
        for (int nb = 0; nb < 4; ++nb)
#pragma unroll
            for (int j = 0; j < 4; ++j)
                es += __expf(2.0f * acc[m][nb][j] * rv[j]);
        ssum += (double)es;
    }
#pragma unroll
    for (int off = 32; off; off >>= 1) ssum += __shfl_down(ssum, off);
    __syncthreads();
    double* red = (double*)smem;
    if (l == 0) red[w] = ssum;
    __syncthreads();
    if (t == 0) {
        double s = 0.0;
#pragma unroll
        for (int i = 0; i < 4; ++i) s += red[i];
        partials[wg] = s;
    }
}

// ---------------- finish: per-batch gather (3 mt x 16 nt), log-ratio, mean --------
__global__ void pcl_finish(const double* __restrict__ partials, float* __restrict__ out) {
    int b = threadIdx.x;   // 64 batches
    double far = 0.0, close = 0.0;
#pragma unroll
    for (int i = 0; i < 3; ++i) {
        int mt = b * 3 + i;
#pragma unroll
        for (int nTile = 0; nTile < 16; ++nTile) {
            double v = partials[mt * 16 + nTile];
            if (nTile < 8) far += v; else close += v;
        }
    }
    double lb = log(far) - log(close);
#pragma unroll
    for (int off = 32; off; off >>= 1) lb += __shfl_down(lb, off);
    if (b == 0) out[0] = (float)(lb * (1.0 / 64.0));
}

extern "C" void kernel_launch(void* const* d_in, const int* in_sizes, int n_in,
                              void* d_out, int out_size, void* d_ws, size_t ws_size,
                              hipStream_t stream) {
    const float* x    = (const float*)d_in[0];
    const float* w    = (const float*)d_in[1];
    const float* bias = (const float*)d_in[2];
    const float* l1   = (const float*)d_in[3];
    const float* l2   = (const float*)d_in[4];
    float* out = (float*)d_out;

    unsigned short* xp   = (unsigned short*)d_ws;                        // 36864*768 bf16 X
    unsigned short* pbuf = (unsigned short*)((char*)d_ws + 56623104);    // 36864*768 bf16 P
    unsigned short* wsW  = (unsigned short*)((char*)d_ws + 113246208);   // 768*768 bf16
    unsigned short* wsL  = (unsigned short*)((char*)d_ws + 114425856);   // 2048*768 bf16
    float* rpnp          = (float*)((char*)d_ws + 117571584);            // 8*36864 f32
    float* rpn           = (float*)((char*)d_ws + 118751232);            // 36864 f32
    double* partials     = (double*)((char*)d_ws + 118898688);           // 3072 f64

    (void)hipFuncSetAttribute((const void*)pcl_k1,
                              hipFuncAttributeMaxDynamicSharedMemorySize, K1_LDS);
    (void)hipFuncSetAttribute((const void*)pcl_k2,
                              hipFuncAttributeMaxDynamicSharedMemorySize, K2_LDS);

    pcl_prep_x<<<9216, 256, 0, stream>>>(x, xp);
    pcl_prep_wl<<<2816, 64, 0, stream>>>(w, l1, l2, wsW, wsL);
    pcl_k1<<<1536, 256, K1_LDS, stream>>>(xp, wsW, bias, pbuf, rpnp);
    pcl_norm<<<144, 256, 0, stream>>>(rpnp, rpn);
    pcl_k2<<<3072, 256, K2_LDS, stream>>>(pbuf, wsL, rpn, partials);
    pcl_finish<<<1, 64, 0, stream>>>(partials, out);
}